// Round 1
// baseline (796.366 us; speedup 1.0000x reference)
//
#include <hip/hip_runtime.h>

// ---------------------------------------------------------------------------
// ChatGLM attention block on MI355X (gfx950), bf16 MFMA pipeline.
//   S=2048, B=1, H=4096, NH=32, HD=128, ROT=64.
// Stages: cvt(hs,Wqkv) -> GEMM1(qkv) -> rope -> attention -> cvt(Wd) -> GEMM2.
// layer_id cancels algebraically; mask is causal (masked logits -> exp==0).
// ---------------------------------------------------------------------------

#define S_LEN 2048
#define NHEAD 32
#define HDIM 128
#define HID 4096

typedef float f32x4 __attribute__((ext_vector_type(4)));
typedef __bf16 bf16x8 __attribute__((ext_vector_type(8)));
typedef __bf16 bf16x4 __attribute__((ext_vector_type(4)));
typedef _Float16 f16x4 __attribute__((ext_vector_type(4)));

__device__ __forceinline__ void gload16(const void* g, void* l) {
  __builtin_amdgcn_global_load_lds(
      (const __attribute__((address_space(1))) void*)g,
      (__attribute__((address_space(3))) void*)l, 16, 0, 0);
}

// ------------------------- f32 -> bf16 convert ----------------------------
__global__ __launch_bounds__(256) void cvt_f32_bf16_kernel(
    const float* __restrict__ in, __bf16* __restrict__ out, int n4) {
  int i = blockIdx.x * 256 + threadIdx.x;
  if (i >= n4) return;
  f32x4 v = *(const f32x4*)(in + (size_t)i * 4);
  bf16x4 o;
  o[0] = (__bf16)v[0]; o[1] = (__bf16)v[1];
  o[2] = (__bf16)v[2]; o[3] = (__bf16)v[3];
  *(bf16x4*)(out + (size_t)i * 4) = o;
}

// ------------------------- GEMM: C = A * B^T + bias -----------------------
// A:[M,K] bf16 row-major, B:[N,K] bf16 row-major (i.e. weight layout),
// bias:[N] f32. OUT_BF16 ? bf16 C : f32 C.  BM=BN=128, BK=32, 256 thr.
template <int OUT_BF16>
__global__ __launch_bounds__(256) void gemm_bt_kernel(
    const __bf16* __restrict__ A, const __bf16* __restrict__ B,
    const float* __restrict__ bias, void* __restrict__ Cout,
    int M, int N, int K, int mtiles) {
  __shared__ __align__(16) __bf16 As[128 * 32];
  __shared__ __align__(16) __bf16 Bs[128 * 32];
  int tid = threadIdx.x;
  // patch swizzle: groups of (mtiles x 8) tiles share A-panels and B-panels in L2
  int bid = blockIdx.x;
  int per_patch = mtiles * 8;
  int p = bid / per_patch, r = bid % per_patch;
  int mt = r % mtiles;
  int nt = p * 8 + r / mtiles;
  int m0 = mt * 128, n0 = nt * 128;

  int w = tid >> 6, l = tid & 63;
  int wm = w >> 1, wn = w & 1;
  int lr = l & 15, lg = l >> 4;

  // staging: chunk c = issue*256+tid covers row c>>2, col (c&3)*8 of the 128x32 tile
  int row0 = tid >> 2, colo = (tid & 3) * 8;
  const __bf16* pA0 = A + (size_t)(m0 + row0) * K + colo;
  const __bf16* pB0 = B + (size_t)(n0 + row0) * K + colo;
  size_t step64 = (size_t)64 * K;
  __bf16* lA0 = As + tid * 8;
  __bf16* lA1 = As + (tid + 256) * 8;
  __bf16* lB0 = Bs + tid * 8;
  __bf16* lB1 = Bs + (tid + 256) * 8;

  f32x4 acc[4][4];
#pragma unroll
  for (int a = 0; a < 4; a++)
#pragma unroll
    for (int b = 0; b < 4; b++) acc[a][b] = 0.f;

  const __bf16* aF = As + (wm * 64 + lr) * 32 + lg * 8;
  const __bf16* bF = Bs + (wn * 64 + lr) * 32 + lg * 8;

  for (int kt = 0; kt < K; kt += 32) {
    gload16(pA0 + kt, lA0);
    gload16(pA0 + step64 + kt, lA1);
    gload16(pB0 + kt, lB0);
    gload16(pB0 + step64 + kt, lB1);
    __syncthreads();
    bf16x8 af[4], bfr[4];
#pragma unroll
    for (int i = 0; i < 4; i++) {
      af[i] = *(const bf16x8*)(aF + i * 16 * 32);
      bfr[i] = *(const bf16x8*)(bF + i * 16 * 32);
    }
#pragma unroll
    for (int mi = 0; mi < 4; mi++)
#pragma unroll
      for (int ni = 0; ni < 4; ni++)
        acc[mi][ni] = __builtin_amdgcn_mfma_f32_16x16x32_bf16(
            af[mi], bfr[ni], acc[mi][ni], 0, 0, 0);
    __syncthreads();
  }

  // epilogue: C/D layout col=lane&15, row=(lane>>4)*4+j  [verified m89/m91]
#pragma unroll
  for (int mi = 0; mi < 4; mi++) {
#pragma unroll
    for (int ni = 0; ni < 4; ni++) {
      int row = m0 + wm * 64 + mi * 16 + lg * 4;
      int col = n0 + wn * 64 + ni * 16 + lr;
      float bv = bias[col];
      f32x4 v = acc[mi][ni];
#pragma unroll
      for (int j = 0; j < 4; j++) {
        float o = v[j] + bv;
        if (OUT_BF16)
          ((__bf16*)Cout)[(size_t)(row + j) * N + col] = (__bf16)o;
        else
          ((float*)Cout)[(size_t)(row + j) * N + col] = o;
      }
    }
  }
}

// ------------------------------- RoPE -------------------------------------
// qkv: [S][NH][384] bf16 (q|k|v per head). Writes Q,K [NH][S][HD] bf16
// (Q scaled by 1/sqrt(HD)), V [NH][S][HD] f16.
__global__ __launch_bounds__(256) void rope_kernel(
    const __bf16* __restrict__ qkv, const int* __restrict__ pos_ids,
    __bf16* __restrict__ Q, __bf16* __restrict__ K, _Float16* __restrict__ V) {
  int s = blockIdx.x;
  int t = threadIdx.x;
  __shared__ float cs[2][2][32];  // [half][cos|sin][i]
  if (t < 64) {
    int half = t >> 5, i = t & 31;
    int p = pos_ids[half * S_LEN + s];
    float f = powf(10000.f, -(float)i / 32.f);
    float ang = (float)p * f;
    cs[half][0][i] = cosf(ang);
    cs[half][1][i] = sinf(ang);
  }
  __syncthreads();
  const __bf16* row = qkv + (size_t)s * (NHEAD * 3 * HDIM);
  const float qscale = 0.08838834764831845f;  // 1/sqrt(128)
  for (int e = t; e < NHEAD * HDIM; e += 256) {
    int h = e >> 7, d = e & 127;
    int half = d >> 6, i = d & 63;
    int ii = i & 31;
    float c = cs[half][0][ii], sn = cs[half][1][ii];
    const __bf16* qh = row + h * 384;
    float qd = (float)qh[d], kd = (float)qh[128 + d];
    int dp = (i < 32) ? d + 32 : d - 32;
    float qp = (float)qh[dp], kp = (float)qh[128 + dp];
    float sgn = (i < 32) ? -1.f : 1.f;
    float qo = qd * c + sgn * qp * sn;
    float ko = kd * c + sgn * kp * sn;
    size_t o = ((size_t)h * S_LEN + s) * HDIM + d;
    Q[o] = (__bf16)(qo * qscale);
    K[o] = (__bf16)ko;
    V[o] = (_Float16)(float)qh[256 + d];
  }
}

// ---------------------------- Flash attention ------------------------------
// grid = NH * (S/64); 4 waves/block, each wave owns a 16-row q tile.
// Swapped QK^T: st = mfma(K,Q) -> D(row=kv, col=q); lane l holds
// P[q=l&15][kv=(l>>4)*4+j] which is exactly the A-fragment of 16x16x16 PV.
__global__ __launch_bounds__(256) void attn_kernel(
    const __bf16* __restrict__ Q, const __bf16* __restrict__ K,
    const _Float16* __restrict__ V, __bf16* __restrict__ ctx) {
  const int nqb = S_LEN / 64;
  int h = blockIdx.x / nqb, qb = blockIdx.x % nqb;
  int w = threadIdx.x >> 6, l = threadIdx.x & 63;
  int lr = l & 15, lg = l >> 4;
  int q0 = qb * 64 + w * 16;
  const __bf16* Qh = Q + (size_t)h * S_LEN * HDIM;
  const __bf16* Kh = K + (size_t)h * S_LEN * HDIM;
  const _Float16* Vh = V + (size_t)h * S_LEN * HDIM;

  bf16x8 qf[4];
#pragma unroll
  for (int kk = 0; kk < 4; kk++)
    qf[kk] = *(const bf16x8*)(Qh + (size_t)(q0 + lr) * HDIM + kk * 32 + lg * 8);

  f32x4 acc[8];
#pragma unroll
  for (int tt = 0; tt < 8; tt++) acc[tt] = 0.f;
  float m = -INFINITY, lsum = 0.f;
  int qg = q0 + lr;

  for (int kv0 = 0; kv0 <= q0; kv0 += 16) {
    f32x4 st = 0.f;
#pragma unroll
    for (int kk = 0; kk < 4; kk++) {
      bf16x8 kf =
          *(const bf16x8*)(Kh + (size_t)(kv0 + lr) * HDIM + kk * 32 + lg * 8);
      st = __builtin_amdgcn_mfma_f32_16x16x32_bf16(kf, qf[kk], st, 0, 0, 0);
    }
    // causal mask + per-q-row (col=lr) online softmax
    float pj[4];
    float tm = -INFINITY;
#pragma unroll
    for (int j = 0; j < 4; j++) {
      int kvg = kv0 + lg * 4 + j;
      float sv = st[j];
      if (kvg > qg) sv = -INFINITY;
      st[j] = sv;
      tm = fmaxf(tm, sv);
    }
    tm = fmaxf(tm, __shfl_xor(tm, 16));
    tm = fmaxf(tm, __shfl_xor(tm, 32));
    float mn = fmaxf(m, tm);
    float sc = __expf(m - mn);
    float ts = 0.f;
    f16x4 pa;
#pragma unroll
    for (int j = 0; j < 4; j++) {
      pj[j] = __expf(st[j] - mn);
      ts += pj[j];
      pa[j] = (_Float16)pj[j];
    }
    ts += __shfl_xor(ts, 16);
    ts += __shfl_xor(ts, 32);
    lsum = lsum * sc + ts;
    m = mn;
    // rescale factors: acc row q = lg*4+j, stats live at lane q (q<16)
    float scj[4];
#pragma unroll
    for (int j = 0; j < 4; j++) scj[j] = __shfl(sc, lg * 4 + j);
#pragma unroll
    for (int tt = 0; tt < 8; tt++) {
      f16x4 vb;
#pragma unroll
      for (int j = 0; j < 4; j++)
        vb[j] = Vh[(size_t)(kv0 + lg * 4 + j) * HDIM + tt * 16 + lr];
      f32x4 a = acc[tt];
#pragma unroll
      for (int j = 0; j < 4; j++) a[j] *= scj[j];
      acc[tt] = __builtin_amdgcn_mfma_f32_16x16x16f16(pa, vb, a, 0, 0, 0);
    }
  }

  float rj[4];
#pragma unroll
  for (int j = 0; j < 4; j++) rj[j] = 1.f / __shfl(lsum, lg * 4 + j);
#pragma unroll
  for (int tt = 0; tt < 8; tt++) {
#pragma unroll
    for (int j = 0; j < 4; j++) {
      int qo = q0 + lg * 4 + j;
      ctx[(size_t)qo * (NHEAD * HDIM) + h * HDIM + tt * 16 + lr] =
          (__bf16)(acc[tt][j] * rj[j]);
    }
  }
}

// ---------------------------------------------------------------------------
extern "C" void kernel_launch(void* const* d_in, const int* in_sizes, int n_in,
                              void* d_out, int out_size, void* d_ws,
                              size_t ws_size, hipStream_t stream) {
  const float* hs = (const float*)d_in[0];
  const int* pos_ids = (const int*)d_in[1];
  // d_in[2] attention_mask: causal triu, folded into kernel.
  // d_in[3] layer_id: cancels algebraically.
  const float* Wqkv = (const float*)d_in[4];
  const float* bqkv = (const float*)d_in[5];
  const float* Wd = (const float*)d_in[6];
  const float* bd = (const float*)d_in[7];
  float* out = (float*)d_out;

  char* ws = (char*)d_ws;
  constexpr size_t OFF_W = 16777216ULL;              // after hsb
  constexpr size_t OFF_QKV = OFF_W + 100663296ULL;   // 117440512
  constexpr size_t OFF_Q = OFF_QKV + 50331648ULL;    // 167772160
  constexpr size_t OFF_K = OFF_Q + 16777216ULL;      // 184549376
  constexpr size_t OFF_V = OFF_K + 16777216ULL;      // 201326592 (+16MB = 218MB)
  __bf16* hsb = (__bf16*)(ws);
  __bf16* wqkvb = (__bf16*)(ws + OFF_W);
  __bf16* wdb = (__bf16*)(ws + OFF_W);  // aliases wqkvb (used after GEMM1)
  __bf16* qkvb = (__bf16*)(ws + OFF_QKV);
  __bf16* ctxb = qkvb;  // aliases qkv (used after rope)
  __bf16* Qb = (__bf16*)(ws + OFF_Q);
  __bf16* Kb = (__bf16*)(ws + OFF_K);
  _Float16* Vb = (_Float16*)(ws + OFF_V);

  // converts
  cvt_f32_bf16_kernel<<<(S_LEN * HID) / 4 / 256, 256, 0, stream>>>(hs, hsb,
                                                                   S_LEN * HID / 4);
  cvt_f32_bf16_kernel<<<(3 * HID * HID) / 4 / 256, 256, 0, stream>>>(
      Wqkv, wqkvb, 3 * HID * HID / 4);

  // GEMM1: [2048,4096] x [12288,4096]^T -> bf16 qkv
  gemm_bt_kernel<1><<<16 * 96, 256, 0, stream>>>(hsb, wqkvb, bqkv, qkvb, S_LEN,
                                                 3 * HID, HID, 16);

  // Wd convert (reuses wqkv region; stream-ordered after GEMM1)
  cvt_f32_bf16_kernel<<<(HID * HID) / 4 / 256, 256, 0, stream>>>(
      Wd, wdb, HID * HID / 4);

  // RoPE + layout transform
  rope_kernel<<<S_LEN, 256, 0, stream>>>(qkvb, pos_ids, Qb, Kb, Vb);

  // attention -> ctx bf16 [S][4096]
  attn_kernel<<<NHEAD * (S_LEN / 64), 256, 0, stream>>>(Qb, Kb, Vb, ctxb);

  // GEMM2: [2048,4096] x [4096,4096]^T + bd -> f32 out
  gemm_bt_kernel<0><<<16 * 32, 256, 0, stream>>>(ctxb, wdb, bd, out, S_LEN,
                                                 HID, HID, 16);
}

// Round 2
// 718.162 us; speedup vs baseline: 1.1089x; 1.1089x over previous
//
#include <hip/hip_runtime.h>

// ---------------------------------------------------------------------------
// ChatGLM attention block on MI355X (gfx950), bf16 MFMA pipeline.
//   S=2048, B=1, H=4096, NH=32, HD=128, ROT=64.
// Stages: cvt(hs,Wqkv) -> GEMM1(qkv) -> rope(+V transpose) -> attention
//         -> cvt(Wd) -> GEMM2.
// layer_id cancels algebraically; mask is causal (masked logits -> exp==0).
// ---------------------------------------------------------------------------

#define S_LEN 2048
#define NHEAD 32
#define HDIM 128
#define HID 4096

typedef float f32x4 __attribute__((ext_vector_type(4)));
typedef __bf16 bf16x8 __attribute__((ext_vector_type(8)));
typedef __bf16 bf16x4 __attribute__((ext_vector_type(4)));
typedef _Float16 f16x4 __attribute__((ext_vector_type(4)));
typedef _Float16 f16x8 __attribute__((ext_vector_type(8)));

__device__ __forceinline__ void gload16(const void* g, void* l) {
  __builtin_amdgcn_global_load_lds(
      (const __attribute__((address_space(1))) void*)g,
      (__attribute__((address_space(3))) void*)l, 16, 0, 0);
}

// ------------------------- f32 -> bf16 convert ----------------------------
__global__ __launch_bounds__(256) void cvt_f32_bf16_kernel(
    const float* __restrict__ in, __bf16* __restrict__ out, int n4) {
  int i = blockIdx.x * 256 + threadIdx.x;
  if (i >= n4) return;
  f32x4 v = *(const f32x4*)(in + (size_t)i * 4);
  bf16x4 o;
  o[0] = (__bf16)v[0]; o[1] = (__bf16)v[1];
  o[2] = (__bf16)v[2]; o[3] = (__bf16)v[3];
  *(bf16x4*)(out + (size_t)i * 4) = o;
}

// ------------------------- GEMM: C = A * B^T + bias -----------------------
template <int OUT_BF16>
__global__ __launch_bounds__(256) void gemm_bt_kernel(
    const __bf16* __restrict__ A, const __bf16* __restrict__ B,
    const float* __restrict__ bias, void* __restrict__ Cout,
    int M, int N, int K, int mtiles) {
  __shared__ __align__(16) __bf16 As[128 * 32];
  __shared__ __align__(16) __bf16 Bs[128 * 32];
  int tid = threadIdx.x;
  int bid = blockIdx.x;
  int per_patch = mtiles * 8;
  int p = bid / per_patch, r = bid % per_patch;
  int mt = r % mtiles;
  int nt = p * 8 + r / mtiles;
  int m0 = mt * 128, n0 = nt * 128;

  int w = tid >> 6, l = tid & 63;
  int wm = w >> 1, wn = w & 1;
  int lr = l & 15, lg = l >> 4;

  int row0 = tid >> 2, colo = (tid & 3) * 8;
  const __bf16* pA0 = A + (size_t)(m0 + row0) * K + colo;
  const __bf16* pB0 = B + (size_t)(n0 + row0) * K + colo;
  size_t step64 = (size_t)64 * K;
  __bf16* lA0 = As + tid * 8;
  __bf16* lA1 = As + (tid + 256) * 8;
  __bf16* lB0 = Bs + tid * 8;
  __bf16* lB1 = Bs + (tid + 256) * 8;

  f32x4 acc[4][4];
#pragma unroll
  for (int a = 0; a < 4; a++)
#pragma unroll
    for (int b = 0; b < 4; b++) acc[a][b] = 0.f;

  const __bf16* aF = As + (wm * 64 + lr) * 32 + lg * 8;
  const __bf16* bF = Bs + (wn * 64 + lr) * 32 + lg * 8;

  for (int kt = 0; kt < K; kt += 32) {
    gload16(pA0 + kt, lA0);
    gload16(pA0 + step64 + kt, lA1);
    gload16(pB0 + kt, lB0);
    gload16(pB0 + step64 + kt, lB1);
    __syncthreads();
    bf16x8 af[4], bfr[4];
#pragma unroll
    for (int i = 0; i < 4; i++) {
      af[i] = *(const bf16x8*)(aF + i * 16 * 32);
      bfr[i] = *(const bf16x8*)(bF + i * 16 * 32);
    }
#pragma unroll
    for (int mi = 0; mi < 4; mi++)
#pragma unroll
      for (int ni = 0; ni < 4; ni++)
        acc[mi][ni] = __builtin_amdgcn_mfma_f32_16x16x32_bf16(
            af[mi], bfr[ni], acc[mi][ni], 0, 0, 0);
    __syncthreads();
  }

#pragma unroll
  for (int mi = 0; mi < 4; mi++) {
#pragma unroll
    for (int ni = 0; ni < 4; ni++) {
      int row = m0 + wm * 64 + mi * 16 + lg * 4;
      int col = n0 + wn * 64 + ni * 16 + lr;
      float bv = bias[col];
      f32x4 v = acc[mi][ni];
#pragma unroll
      for (int j = 0; j < 4; j++) {
        float o = v[j] + bv;
        if (OUT_BF16)
          ((__bf16*)Cout)[(size_t)(row + j) * N + col] = (__bf16)o;
        else
          ((float*)Cout)[(size_t)(row + j) * N + col] = o;
      }
    }
  }
}

// ------------------------------- RoPE -------------------------------------
// Block = (head h, 64-s chunk). Reads qkv [S][NH*384] bf16.
// Writes Q,K [NH][S][HD] bf16 (Q scaled by 1/sqrt(HD)), VT [NH][HD][S] f16.
__global__ __launch_bounds__(256) void rope_kernel(
    const __bf16* __restrict__ qkv, const int* __restrict__ pos_ids,
    __bf16* __restrict__ Q, __bf16* __restrict__ K, _Float16* __restrict__ VT) {
  int h = blockIdx.x & 31, sb = blockIdx.x >> 5;
  int s0 = sb * 64;
  int t = threadIdx.x;
  __shared__ float cs[64][2][2][32];      // [s_local][half][cos|sin][freq] 32KB
  __shared__ _Float16 vs[64][132];        // padded V stage (~16.5KB)

  // trig table: 64 s x 2 halves x 32 freqs
  for (int idx = t; idx < 64 * 64; idx += 256) {
    int sl = idx >> 6, half = (idx >> 5) & 1, i = idx & 31;
    int p = pos_ids[half * S_LEN + s0 + sl];
    float f = powf(10000.f, -(float)i / 32.f);
    float ang = (float)p * f;
    cs[sl][half][0][i] = cosf(ang);
    cs[sl][half][1][i] = sinf(ang);
  }
  // stage V (bf16 -> f16) into LDS, row-major [s][d]
#pragma unroll
  for (int c = 0; c < 4; c++) {
    int chunk = c * 256 + t;                 // 1024 chunks of 8
    int slv = chunk >> 4, co = (chunk & 15) * 8;
    const __bf16* vsrc =
        qkv + (size_t)(s0 + slv) * (NHEAD * 3 * HDIM) + h * 384 + 256 + co;
    bf16x8 vv = *(const bf16x8*)vsrc;
    f16x4 a, b;
#pragma unroll
    for (int j = 0; j < 4; j++) {
      a[j] = (_Float16)(float)vv[j];
      b[j] = (_Float16)(float)vv[4 + j];
    }
    *(f16x4*)&vs[slv][co] = a;
    *(f16x4*)&vs[slv][co + 4] = b;
  }
  __syncthreads();

  // rope on q,k: 4 threads per s; role: 0=q half0, 1=q half1, 2=k half0, 3=k half1
  {
    int sl = t >> 2, role = t & 3;
    int isK = role >> 1, half = role & 1;
    const __bf16* src = qkv + (size_t)(s0 + sl) * (NHEAD * 3 * HDIM) + h * 384 +
                        isK * 128 + half * 64;
    float scale = isK ? 1.f : 0.08838834764831845f;  // 1/sqrt(128)
    float x[64];
    bf16x8 buf[8];
#pragma unroll
    for (int c = 0; c < 8; c++) buf[c] = *(const bf16x8*)(src + c * 8);
#pragma unroll
    for (int c = 0; c < 8; c++)
#pragma unroll
      for (int j = 0; j < 8; j++) x[c * 8 + j] = (float)buf[c][j];
    bf16x8 ob[8];
#pragma unroll
    for (int i = 0; i < 64; i++) {
      int ii = i & 31;
      float cv = cs[sl][half][0][ii], sv = cs[sl][half][1][ii];
      float partner = (i < 32) ? x[i + 32] : x[i - 32];
      float sgn = (i < 32) ? -1.f : 1.f;
      float o = (x[i] * cv + sgn * partner * sv) * scale;
      ob[i >> 3][i & 7] = (__bf16)o;
    }
    __bf16* dst = (isK ? K : Q) + ((size_t)h * S_LEN + s0 + sl) * HDIM + half * 64;
#pragma unroll
    for (int c = 0; c < 8; c++) *(bf16x8*)(dst + c * 8) = ob[c];
  }

  // write VT [h][d][s]: transpose out of LDS, 16B stores along s
#pragma unroll
  for (int c = 0; c < 4; c++) {
    int chunk = c * 256 + t;                 // 1024 chunks of 8
    int d = chunk >> 3, so = (chunk & 7) * 8;
    f16x8 o;
#pragma unroll
    for (int j = 0; j < 8; j++) o[j] = vs[so + j][d];
    *(f16x8*)(VT + ((size_t)h * HDIM + d) * S_LEN + s0 + so) = o;
  }
}

// ---------------------------- Flash attention ------------------------------
// grid = 512: h = b&31, qb = 15 - (b>>5)  (heavy q-tiles dispatched first).
// 4 waves/block; wave owns 32 q rows (two 16-row fragments A,B).
// Swapped QK^T: st = mfma(K,Q) -> lane l holds P[q=l&15][kv=(l>>4)*4+j],
// which is exactly the A-fragment of the 16x16x16 f16 PV MFMA.
__global__ __launch_bounds__(256, 2) void attn_kernel(
    const __bf16* __restrict__ Q, const __bf16* __restrict__ K,
    const _Float16* __restrict__ VT, __bf16* __restrict__ ctx) {
  int b = blockIdx.x;
  int h = b & 31;
  int qb = 15 - (b >> 5);
  int w = threadIdx.x >> 6, l = threadIdx.x & 63;
  int lr = l & 15, lg = l >> 4;
  int q0 = qb * 128 + w * 32;  // frag A: rows q0..q0+15, frag B: q0+16..q0+31
  const __bf16* Qh = Q + (size_t)h * S_LEN * HDIM;
  const __bf16* Kh = K + (size_t)h * S_LEN * HDIM;
  const _Float16* Vh = VT + (size_t)h * HDIM * S_LEN;

  bf16x8 qfA[4], qfB[4];
#pragma unroll
  for (int kk = 0; kk < 4; kk++) {
    qfA[kk] = *(const bf16x8*)(Qh + (size_t)(q0 + lr) * HDIM + kk * 32 + lg * 8);
    qfB[kk] =
        *(const bf16x8*)(Qh + (size_t)(q0 + 16 + lr) * HDIM + kk * 32 + lg * 8);
  }

  f32x4 accA[8], accB[8];
#pragma unroll
  for (int tt = 0; tt < 8; tt++) { accA[tt] = 0.f; accB[tt] = 0.f; }
  float mA = -INFINITY, lsA = 0.f, mB = -INFINITY, lsB = 0.f;
  int qgA = q0 + lr, qgB = q0 + 16 + lr;
  int qmax = q0 + 31;

  for (int kv0 = 0; kv0 <= qmax; kv0 += 16) {
    f32x4 stA = 0.f, stB = 0.f;
#pragma unroll
    for (int kk = 0; kk < 4; kk++) {
      bf16x8 kf =
          *(const bf16x8*)(Kh + (size_t)(kv0 + lr) * HDIM + kk * 32 + lg * 8);
      stA = __builtin_amdgcn_mfma_f32_16x16x32_bf16(kf, qfA[kk], stA, 0, 0, 0);
      stB = __builtin_amdgcn_mfma_f32_16x16x32_bf16(kf, qfB[kk], stB, 0, 0, 0);
    }
    // causal mask + per-q-row max (q = col = lr; kv = row = lg*4+j)
    float tmA = -INFINITY, tmB = -INFINITY;
#pragma unroll
    for (int j = 0; j < 4; j++) {
      int kvg = kv0 + lg * 4 + j;
      if (kvg > qgA) stA[j] = -INFINITY;
      if (kvg > qgB) stB[j] = -INFINITY;
      tmA = fmaxf(tmA, stA[j]);
      tmB = fmaxf(tmB, stB[j]);
    }
    tmA = fmaxf(tmA, __shfl_xor(tmA, 16));
    tmA = fmaxf(tmA, __shfl_xor(tmA, 32));
    tmB = fmaxf(tmB, __shfl_xor(tmB, 16));
    tmB = fmaxf(tmB, __shfl_xor(tmB, 32));
    int need = __any((tmA > mA) || (tmB > mB));
    float mnA = fmaxf(mA, tmA), mnB = fmaxf(mB, tmB);

    f16x4 paA, paB;
    float tsA = 0.f, tsB = 0.f;
#pragma unroll
    for (int j = 0; j < 4; j++) {
      float pA = __expf(stA[j] - mnA);
      float pB = __expf(stB[j] - mnB);
      tsA += pA; tsB += pB;
      paA[j] = (_Float16)pA; paB[j] = (_Float16)pB;
    }
    tsA += __shfl_xor(tsA, 16);
    tsA += __shfl_xor(tsA, 32);
    tsB += __shfl_xor(tsB, 16);
    tsB += __shfl_xor(tsB, 32);

    if (need) {
      float scA = __expf(mA - mnA), scB = __expf(mB - mnB);
      lsA = lsA * scA + tsA;
      lsB = lsB * scB + tsB;
      float sAj[4], sBj[4];
#pragma unroll
      for (int j = 0; j < 4; j++) {
        sAj[j] = __shfl(scA, lg * 4 + j);
        sBj[j] = __shfl(scB, lg * 4 + j);
      }
#pragma unroll
      for (int tt = 0; tt < 8; tt++)
#pragma unroll
        for (int j = 0; j < 4; j++) {
          accA[tt][j] *= sAj[j];
          accB[tt][j] *= sBj[j];
        }
    } else {
      lsA += tsA;
      lsB += tsB;
    }
    mA = mnA; mB = mnB;

#pragma unroll
    for (int tt = 0; tt < 8; tt++) {
      f16x4 vb =
          *(const f16x4*)(Vh + (size_t)(tt * 16 + lr) * S_LEN + kv0 + lg * 4);
      accA[tt] = __builtin_amdgcn_mfma_f32_16x16x16f16(paA, vb, accA[tt], 0, 0, 0);
      accB[tt] = __builtin_amdgcn_mfma_f32_16x16x16f16(paB, vb, accB[tt], 0, 0, 0);
    }
  }

  float rA[4], rB[4];
#pragma unroll
  for (int j = 0; j < 4; j++) {
    rA[j] = 1.f / __shfl(lsA, lg * 4 + j);
    rB[j] = 1.f / __shfl(lsB, lg * 4 + j);
  }
#pragma unroll
  for (int tt = 0; tt < 8; tt++) {
#pragma unroll
    for (int j = 0; j < 4; j++) {
      int qoA = q0 + lg * 4 + j;
      int qoB = q0 + 16 + lg * 4 + j;
      ctx[(size_t)qoA * (NHEAD * HDIM) + h * HDIM + tt * 16 + lr] =
          (__bf16)(accA[tt][j] * rA[j]);
      ctx[(size_t)qoB * (NHEAD * HDIM) + h * HDIM + tt * 16 + lr] =
          (__bf16)(accB[tt][j] * rB[j]);
    }
  }
}

// ---------------------------------------------------------------------------
extern "C" void kernel_launch(void* const* d_in, const int* in_sizes, int n_in,
                              void* d_out, int out_size, void* d_ws,
                              size_t ws_size, hipStream_t stream) {
  const float* hs = (const float*)d_in[0];
  const int* pos_ids = (const int*)d_in[1];
  const float* Wqkv = (const float*)d_in[4];
  const float* bqkv = (const float*)d_in[5];
  const float* Wd = (const float*)d_in[6];
  const float* bd = (const float*)d_in[7];
  float* out = (float*)d_out;

  char* ws = (char*)d_ws;
  constexpr size_t OFF_W = 16777216ULL;
  constexpr size_t OFF_QKV = OFF_W + 100663296ULL;
  constexpr size_t OFF_Q = OFF_QKV + 50331648ULL;
  constexpr size_t OFF_K = OFF_Q + 16777216ULL;
  constexpr size_t OFF_V = OFF_K + 16777216ULL;
  __bf16* hsb = (__bf16*)(ws);
  __bf16* wqkvb = (__bf16*)(ws + OFF_W);
  __bf16* wdb = (__bf16*)(ws + OFF_W);  // aliases wqkvb (used after GEMM1)
  __bf16* qkvb = (__bf16*)(ws + OFF_QKV);
  __bf16* ctxb = qkvb;                  // aliases qkv (used after rope)
  __bf16* Qb = (__bf16*)(ws + OFF_Q);
  __bf16* Kb = (__bf16*)(ws + OFF_K);
  _Float16* Vtb = (_Float16*)(ws + OFF_V);

  cvt_f32_bf16_kernel<<<(S_LEN * HID) / 4 / 256, 256, 0, stream>>>(
      hs, hsb, S_LEN * HID / 4);
  cvt_f32_bf16_kernel<<<(3 * HID * HID) / 4 / 256, 256, 0, stream>>>(
      Wqkv, wqkvb, 3 * HID * HID / 4);

  gemm_bt_kernel<1><<<16 * 96, 256, 0, stream>>>(hsb, wqkvb, bqkv, qkvb, S_LEN,
                                                 3 * HID, HID, 16);

  cvt_f32_bf16_kernel<<<(HID * HID) / 4 / 256, 256, 0, stream>>>(
      Wd, wdb, HID * HID / 4);

  rope_kernel<<<NHEAD * (S_LEN / 64), 256, 0, stream>>>(qkvb, pos_ids, Qb, Kb,
                                                        Vtb);

  attn_kernel<<<NHEAD * (S_LEN / 128), 256, 0, stream>>>(Qb, Kb, Vtb, ctxb);

  gemm_bt_kernel<0><<<16 * 32, 256, 0, stream>>>(ctxb, wdb, bd, out, S_LEN,
                                                 HID, HID, 16);
}